// Round 7
// baseline (493.905 us; speedup 1.0000x reference)
//
#include <hip/hip_runtime.h>

typedef unsigned long long u64;
typedef unsigned short u16;

#define PRE   2000
#define POST  300
#define NCLS  5
#define CAP   512            // max clusters/dets per class (input has ~400/class)
#define SORTN 2048
#define NTH   (NCLS * 64)    // 320 threads = 5 waves, one class per wave

// Exact threshold midpoint: fl32(inter/uni) > 0.55f  <=>  inter >= MID*uni (uni>0).
// MID = 0.55f + 2^-25; MID*(24-bit uni) exact in f64 -> bit-exact predicate.
// Validated: absmax == 0.0 in rounds 3-6.
#define MID 0x1.19999A8p-1

__device__ __forceinline__ float rdlanef(float v, int l) {
    return __int_as_float(__builtin_amdgcn_readlane(__float_as_int(v), l));
}

// CREATE into slot regs K (owner lane os): mean v0..3, area va, solo sums u0..3/sc, meta
#define WR_CREATE(K)                                                              \
    if (lane == os) {                                                             \
        cm0[K] = v0; cm1[K] = v1; cm2[K] = v2; cm3[K] = v3; ca[K] = va;           \
        cs0[K] = u0; cs1[K] = u1; cs2[K] = u2; cs3[K] = u3; css[K] = sc;          \
        cg[K] = gmeta;                                                            \
    }
// MERGE into slot regs K (owner lane oc): exact ref op order (mul round, add round),
// then uniform read-back of the new sums
#define MERGE(K)                                                                  \
    if (lane == oc) {                                                             \
        cs0[K] = cs0[K] + sc * bx0; cs1[K] = cs1[K] + sc * bx1;                   \
        cs2[K] = cs2[K] + sc * bx2; cs3[K] = cs3[K] + sc * bx3;                   \
        css[K] = css[K] + sc; cg[K] += 0x10000;                                   \
    }                                                                             \
    t0 = rdlanef(cs0[K], oc); t1 = rdlanef(cs1[K], oc);                           \
    t2 = rdlanef(cs2[K], oc); t3 = rdlanef(cs3[K], oc);                           \
    ts = rdlanef(css[K], oc);
#define WR_MEAN(K) if (lane == oc) { cm0[K]=nm0; cm1[K]=nm1; cm2[K]=nm2; cm3[K]=nm3; ca[K]=na; }

__global__ __launch_bounds__(NTH, 1) void wbf_fused(const float* __restrict__ x,
                                                    float* __restrict__ out) {
#pragma clang fp contract(off)
    // LDS: 40960 (means, output stage) + 5120 (det lists) + 16384 (keys) + 4 = 62,468 B
    __shared__ float4 s_mean[NCLS * CAP];
    __shared__ u16    s_aux[NCLS * CAP];
    __shared__ u64    s_keys[SORTN];      // aliased as class cache in P0/P1
    __shared__ int    s_total;

    const int tid  = threadIdx.x;
    const int w    = tid >> 6;      // class id == wave id
    const int lane = tid & 63;
    const float mycls = (float)w;
    const int base = w * CAP;

    float* s_clsTmp = (float*)s_keys;   // 2000 floats, dead after P1

    // ---- P0: cooperative load of class fields ----
    for (int t = tid; t < PRE; t += NTH) s_clsTmp[t] = x[t * 6 + 5];
    if (tid == 0) s_total = 0;
    __syncthreads();

    // ---- P1: per-wave order-preserving compaction of my class's det indices ----
    int myn = 0;
    for (int t0 = 0; t0 < PRE; t0 += 64) {
        const int t = t0 + lane;
        const bool p = (t < PRE) && (s_clsTmp[t] == mycls);
        const u64 mask = __ballot(p);
        const int off = __popcll(mask & (((u64)1 << lane) - 1));
        const int pos = myn + off;
        if (p && pos < CAP) s_aux[base + pos] = (u16)t;
        myn += __popcll(mask);
    }
    if (myn > CAP) myn = CAP;
    __syncthreads();   // all waves done with s_clsTmp before s_keys reuse

    // ---- P1.5: preload dets (lane-distributed regs) + precompute solo means ----
    // det rank r: lane r&63, reg r>>6.  cluster slot j: lane j&63, reg j>>6.
    float rb0[8], rb1[8], rb2[8], rb3[8], rsc[8];     // det fields
    int   rg[8];                                      // det global index
    float q0[8], q1[8], q2[8], q3[8];                 // solo means (create mean)
    float cm0[8], cm1[8], cm2[8], cm3[8], ca[8];      // cluster means + cached area
    float cs0[8], cs1[8], cs2[8], cs3[8], css[8];     // cluster sums (slot-keyed)
    int   cg[8];                                      // slot meta: cnt<<16 | first_g
    #pragma unroll
    for (int k = 0; k < 8; ++k) {
        const int rr = k * 64 + lane;
        rb0[k] = 0.f; rb1[k] = 0.f; rb2[k] = 0.f; rb3[k] = 0.f; rsc[k] = 0.f; rg[k] = 0;
        cm0[k] = 0.f; cm1[k] = 0.f; cm2[k] = 0.f; cm3[k] = 0.f; ca[k] = 0.f;
        cs0[k] = 0.f; cs1[k] = 0.f; cs2[k] = 0.f; cs3[k] = 0.f; css[k] = 0.f; cg[k] = 0;
        if (rr < myn) {
            const int g = s_aux[base + rr];
            const float* p = x + g * 6;
            const float2 f01 = *(const float2*)p;
            const float2 f23 = *(const float2*)(p + 2);
            const float2 f45 = *(const float2*)(p + 4);
            rb0[k] = f01.x; rb1[k] = f01.y; rb2[k] = f23.x; rb3[k] = f23.y;
            rsc[k] = f45.x; rg[k] = g;
        }
        // solo mean with exact reference op order: fl(sc*b) then / sc
        const float d = (rr < myn) ? rsc[k] : 1.0f;
        q0[k] = (rsc[k] * rb0[k]) / d; q1[k] = (rsc[k] * rb1[k]) / d;
        q2[k] = (rsc[k] * rb2[k]) / d; q3[k] = (rsc[k] * rb3[k]) / d;
    }

    // ---- P2: per-wave sequential WBF scan — all state in registers ----
    int nc = 0;
    #pragma unroll
    for (int k = 0; k < 8; ++k) {
        const int r0 = k * 64;
        if (r0 < myn) {
            const int iend = (myn - r0 < 64) ? (myn - r0) : 64;
            for (int i = 0; i < iend; ++i) {
                // det broadcast via v_readlane (no DS ops)
                const float bx0 = rdlanef(rb0[k], i);
                const float bx1 = rdlanef(rb1[k], i);
                const float bx2 = rdlanef(rb2[k], i);
                const float bx3 = rdlanef(rb3[k], i);
                const float sc  = rdlanef(rsc[k], i);
                const float a1 = (bx2 - bx0) * (bx3 - bx1);
                // create-path values (independent of scan -> hoisted off the chain)
                const float v0 = rdlanef(q0[k], i), v1 = rdlanef(q1[k], i);
                const float v2 = rdlanef(q2[k], i), v3 = rdlanef(q3[k], i);
                const float va = (v2 - v0) * (v3 - v1);
                const float u0 = sc * bx0, u1 = sc * bx1, u2 = sc * bx2, u3 = sc * bx3;
                const int gmeta = (1 << 16) | __builtin_amdgcn_readlane(rg[k], i);

                // register-resident scan: cluster j = kb*64 + lane
                int foundj = -1;
                #pragma unroll
                for (int kb = 0; kb < 8; ++kb) {
                    if (kb * 64 < nc) {
                        const int j = kb * 64 + lane;
                        const float ltx = fmaxf(bx0, cm0[kb]), lty = fmaxf(bx1, cm1[kb]);
                        const float rbx = fminf(bx2, cm2[kb]), rby = fminf(bx3, cm3[kb]);
                        const float wd = fmaxf(rbx - ltx, 0.f), hg = fmaxf(rby - lty, 0.f);
                        const float inter = wd * hg;
                        const float uni = (a1 + ca[kb]) - inter;
                        const bool pred = (j < nc) && (uni > 0.f) &&
                                          ((double)inter >= MID * (double)uni);
                        const u64 mk = __ballot(pred);
                        if (foundj < 0 && mk) foundj = kb * 64 + (int)__ffsll(mk) - 1;
                    }
                }

                if (foundj < 0) {
                    // CREATE: predicated register writes only — zero chain arithmetic
                    const int ks = nc >> 6, os = nc & 63;
                    switch (ks) {
                        case 0: WR_CREATE(0) break; case 1: WR_CREATE(1) break;
                        case 2: WR_CREATE(2) break; case 3: WR_CREATE(3) break;
                        case 4: WR_CREATE(4) break; case 5: WR_CREATE(5) break;
                        case 6: WR_CREATE(6) break; default: WR_CREATE(7) break;
                    }
                    nc++;
                } else {
                    // MERGE (rare): update slot-owner sums, refresh mean (exact IEEE)
                    const int kc = foundj >> 6, oc = foundj & 63;
                    float t0, t1, t2, t3, ts;
                    switch (kc) {
                        case 0: MERGE(0) break; case 1: MERGE(1) break;
                        case 2: MERGE(2) break; case 3: MERGE(3) break;
                        case 4: MERGE(4) break; case 5: MERGE(5) break;
                        case 6: MERGE(6) break; default: MERGE(7) break;
                    }
                    const float nm0 = t0 / ts, nm1 = t1 / ts;
                    const float nm2 = t2 / ts, nm3 = t3 / ts;
                    const float na = (nm2 - nm0) * (nm3 - nm1);
                    switch (kc) {
                        case 0: WR_MEAN(0) break; case 1: WR_MEAN(1) break;
                        case 2: WR_MEAN(2) break; case 3: WR_MEAN(3) break;
                        case 4: WR_MEAN(4) break; case 5: WR_MEAN(5) break;
                        case 6: WR_MEAN(6) break; default: WR_MEAN(7) break;
                    }
                }
            }
        }
    }

    // ---- P2.5: materialize means to LDS for the output gather ----
    #pragma unroll
    for (int kb = 0; kb < 8; ++kb) {
        const int j = kb * 64 + lane;
        if (j < nc) s_mean[base + j] = make_float4(cm0[kb], cm1[kb], cm2[kb], cm3[kb]);
    }

    // ---- P3: slot-parallel sort-key build (score desc, first-det-idx asc) ----
    __syncthreads();
    int mybase = 0;
    if (lane == 0 && nc > 0) mybase = atomicAdd(&s_total, nc);
    mybase = __shfl(mybase, 0);
    #pragma unroll
    for (int kb = 0; kb < 8; ++kb) {
        const int j = kb * 64 + lane;
        if (j < nc) {
            const int cnt = cg[kb] >> 16;                 // >= 1
            const int g   = cg[kb] & 0xFFFF;              // first det global index
            const float score = css[kb] / (float)cnt;     // exact IEEE div
            const unsigned sb = __float_as_uint(score);   // score > 0: bits monotone
            const int id = base + j;
            u64 key = ((u64)sb << 32) | ((u64)(unsigned)(0xFFFF - g) << 16) | (u64)id;
            s_keys[mybase + j] = ~key;   // ascending sort of ~key == descending of key
        }
    }
    __syncthreads();
    const int n = s_total;
    for (int i = n + tid; i < SORTN; i += NTH) s_keys[i] = ~0ull;
    __syncthreads();

    // ---- P4: bitonic sort, ascending ----
    for (int kk = 2; kk <= SORTN; kk <<= 1) {
        for (int jj = kk >> 1; jj > 0; jj >>= 1) {
            for (int i = tid; i < SORTN; i += NTH) {
                const int ixj = i ^ jj;
                if (ixj > i) {
                    const u64 a = s_keys[i], b = s_keys[ixj];
                    const bool up = ((i & kk) == 0);
                    if ((a > b) == up) { s_keys[i] = b; s_keys[ixj] = a; }
                }
            }
            __syncthreads();
        }
    }

    // ---- P5: emit top-300 ----
    for (int r = tid; r < POST; r += NTH) {
        float* o = out + r * 6;
        if (r < n) {
            const u64 key = ~s_keys[r];
            const int id = (int)(key & 0xFFFFull);
            const float4 mn = s_mean[id];
            o[0] = mn.x; o[1] = mn.y; o[2] = mn.z; o[3] = mn.w;
            o[4] = __uint_as_float((unsigned)(key >> 32));
            o[5] = (float)(id >> 9);   // id / CAP == class
        } else {
            o[0] = 0.f; o[1] = 0.f; o[2] = 0.f; o[3] = 0.f; o[4] = 0.f; o[5] = 0.f;
        }
    }
}

extern "C" void kernel_launch(void* const* d_in, const int* in_sizes, int n_in,
                              void* d_out, int out_size, void* d_ws, size_t ws_size,
                              hipStream_t stream) {
    const float* x = (const float*)d_in[0];
    float* out = (float*)d_out;
    wbf_fused<<<1, NTH, 0, stream>>>(x, out);
}

// Round 8
// 445.348 us; speedup vs baseline: 1.1090x; 1.1090x over previous
//
#include <hip/hip_runtime.h>

typedef unsigned long long u64;
typedef unsigned short u16;

#define PRE   2000
#define POST  300
#define NCLS  5
#define CAP   512            // max clusters/dets per class (input has ~400/class)
#define SORTN 2048

// Exact threshold midpoint: fl32(inter/uni) > 0.55f  <=>  inter >= MID*uni (uni>0).
// MID = 0.55f + 2^-25; MID*(24-bit uni) exact in f64 -> bit-exact predicate.
// Validated: absmax == 0.0 in rounds 3-7.
#define MID 0x1.19999A8p-1

__device__ __forceinline__ float rdlanef(float v, int l) {
    return __int_as_float(__builtin_amdgcn_readlane(__float_as_int(v), l));
}

// CREATE into slot regs K (owner lane os): mean v0..3, area va, solo sums u0..3/sc, meta
#define WR_CREATE(K)                                                              \
    if (lane == os) {                                                             \
        cm0[K] = v0; cm1[K] = v1; cm2[K] = v2; cm3[K] = v3; ca[K] = va;           \
        cs0[K] = u0; cs1[K] = u1; cs2[K] = u2; cs3[K] = u3; css[K] = sc;          \
        cg[K] = gmeta;                                                            \
    }
// MERGE into slot regs K — fully owner-local: sums += sc*b (exact ref op order),
// mean = sums/ss (exact IEEE div), cached area refreshed. No cross-lane traffic.
#define MERGE(K)                                                                  \
    if (lane == oc) {                                                             \
        const float ns0 = cs0[K] + sc * bx0, ns1 = cs1[K] + sc * bx1;             \
        const float ns2 = cs2[K] + sc * bx2, ns3 = cs3[K] + sc * bx3;             \
        const float nss = css[K] + sc;                                            \
        cs0[K] = ns0; cs1[K] = ns1; cs2[K] = ns2; cs3[K] = ns3; css[K] = nss;     \
        cg[K] += 0x10000;                                                         \
        const float nm0 = ns0 / nss, nm1 = ns1 / nss;                             \
        const float nm2 = ns2 / nss, nm3 = ns3 / nss;                             \
        cm0[K] = nm0; cm1[K] = nm1; cm2[K] = nm2; cm3[K] = nm3;                   \
        ca[K] = (nm2 - nm0) * (nm3 - nm1);                                        \
    }

// ---------- kernel 1: one wave per class, full 512-VGPR budget ----------
__global__ __launch_bounds__(64, 1) void wbf_scan(const float* __restrict__ x,
                                                  float* __restrict__ recs,
                                                  int* __restrict__ cnts) {
#pragma clang fp contract(off)
    __shared__ u16 s_list[CAP];   // my class's det indices (1 KB LDS)

    const int lane = threadIdx.x;
    const int w = blockIdx.x;
    const float mycls = (float)w;

    // ---- compaction: order-preserving list of my class's dets (single wave) ----
    int myn = 0;
    for (int t0 = 0; t0 < PRE; t0 += 64) {
        const int t = t0 + lane;
        const bool p = (t < PRE) && (x[t * 6 + 5] == mycls);
        const u64 mask = __ballot(p);
        const int pos = myn + __popcll(mask & (((u64)1 << lane) - 1));
        if (p && pos < CAP) s_list[pos] = (u16)t;
        myn += __popcll(mask);
    }
    if (myn > CAP) myn = CAP;

    // ---- preload dets to lane-distributed regs + precompute solo means ----
    // det rank r: lane r&63, reg r>>6.  cluster slot j: lane j&63, reg j>>6.
    float rb0[8], rb1[8], rb2[8], rb3[8], rsc[8];     // det fields
    int   rg[8];                                      // det global index
    float q0[8], q1[8], q2[8], q3[8];                 // solo means (create mean)
    float cm0[8], cm1[8], cm2[8], cm3[8], ca[8];      // cluster means + cached area
    float cs0[8], cs1[8], cs2[8], cs3[8], css[8];     // cluster sums (slot-keyed)
    int   cg[8];                                      // slot meta: cnt<<16 | first_g
    #pragma unroll
    for (int k = 0; k < 8; ++k) {
        const int rr = k * 64 + lane;
        rb0[k] = 0.f; rb1[k] = 0.f; rb2[k] = 0.f; rb3[k] = 0.f; rsc[k] = 0.f; rg[k] = 0;
        cm0[k] = 0.f; cm1[k] = 0.f; cm2[k] = 0.f; cm3[k] = 0.f; ca[k] = 0.f;
        cs0[k] = 0.f; cs1[k] = 0.f; cs2[k] = 0.f; cs3[k] = 0.f; css[k] = 0.f; cg[k] = 0;
        if (rr < myn) {
            const int g = s_list[rr];
            const float* p = x + g * 6;
            const float2 f01 = *(const float2*)p;
            const float2 f23 = *(const float2*)(p + 2);
            const float2 f45 = *(const float2*)(p + 4);
            rb0[k] = f01.x; rb1[k] = f01.y; rb2[k] = f23.x; rb3[k] = f23.y;
            rsc[k] = f45.x; rg[k] = g;
        }
        // solo mean, exact reference op order: fl(sc*b) then / sc
        const float d = (rr < myn) ? rsc[k] : 1.0f;
        q0[k] = (rsc[k] * rb0[k]) / d; q1[k] = (rsc[k] * rb1[k]) / d;
        q2[k] = (rsc[k] * rb2[k]) / d; q3[k] = (rsc[k] * rb3[k]) / d;
    }

    // ---- sequential WBF scan: all state in registers, zero DS/VMEM on chain ----
    int nc = 0;
    #pragma unroll
    for (int k = 0; k < 8; ++k) {
        const int r0 = k * 64;
        if (r0 < myn) {
            const int iend = (myn - r0 < 64) ? (myn - r0) : 64;
            for (int i = 0; i < iend; ++i) {
                // det broadcast via v_readlane (VALU->SGPR, no DS)
                const float bx0 = rdlanef(rb0[k], i);
                const float bx1 = rdlanef(rb1[k], i);
                const float bx2 = rdlanef(rb2[k], i);
                const float bx3 = rdlanef(rb3[k], i);
                const float sc  = rdlanef(rsc[k], i);
                const float a1 = (bx2 - bx0) * (bx3 - bx1);
                // create-path values, hoisted off the decision chain
                const float v0 = rdlanef(q0[k], i), v1 = rdlanef(q1[k], i);
                const float v2 = rdlanef(q2[k], i), v3 = rdlanef(q3[k], i);
                const float va = (v2 - v0) * (v3 - v1);
                const float u0 = sc * bx0, u1 = sc * bx1, u2 = sc * bx2, u3 = sc * bx3;
                const int gmeta = (1 << 16) | __builtin_amdgcn_readlane(rg[k], i);

                // register-resident scan: cluster j = kb*64 + lane
                int foundj = -1;
                #pragma unroll
                for (int kb = 0; kb < 8; ++kb) {
                    if (kb * 64 < nc) {
                        const int j = kb * 64 + lane;
                        const float ltx = fmaxf(bx0, cm0[kb]), lty = fmaxf(bx1, cm1[kb]);
                        const float rbx = fminf(bx2, cm2[kb]), rby = fminf(bx3, cm3[kb]);
                        const float wd = fmaxf(rbx - ltx, 0.f), hg = fmaxf(rby - lty, 0.f);
                        const float inter = wd * hg;
                        const float uni = (a1 + ca[kb]) - inter;
                        const bool pred = (j < nc) && (uni > 0.f) &&
                                          ((double)inter >= MID * (double)uni);
                        const u64 mk = __ballot(pred);
                        if (foundj < 0 && mk) foundj = kb * 64 + (int)__ffsll(mk) - 1;
                    }
                }

                if (foundj < 0) {
                    const int ks = nc >> 6, os = nc & 63;
                    switch (ks) {
                        case 0: WR_CREATE(0) break; case 1: WR_CREATE(1) break;
                        case 2: WR_CREATE(2) break; case 3: WR_CREATE(3) break;
                        case 4: WR_CREATE(4) break; case 5: WR_CREATE(5) break;
                        case 6: WR_CREATE(6) break; default: WR_CREATE(7) break;
                    }
                    nc++;
                } else {
                    const int kc = foundj >> 6, oc = foundj & 63;
                    switch (kc) {
                        case 0: MERGE(0) break; case 1: MERGE(1) break;
                        case 2: MERGE(2) break; case 3: MERGE(3) break;
                        case 4: MERGE(4) break; case 5: MERGE(5) break;
                        case 6: MERGE(6) break; default: MERGE(7) break;
                    }
                }
            }
        }
    }

    // ---- emit records: [m0 m1 m2 m3 score g_int -- --] x 8 floats per slot ----
    #pragma unroll
    for (int kb = 0; kb < 8; ++kb) {
        const int j = kb * 64 + lane;
        if (j < nc) {
            float* r = recs + (size_t)(w * CAP + j) * 8;
            r[0] = cm0[kb]; r[1] = cm1[kb]; r[2] = cm2[kb]; r[3] = cm3[kb];
            const int cnt = cg[kb] >> 16;                 // >= 1
            r[4] = css[kb] / (float)cnt;                  // exact IEEE div (mean score)
            ((int*)r)[5] = cg[kb] & 0xFFFF;               // first det global index
        }
    }
    if (lane == 0) cnts[w] = nc;
}

// ---------- kernel 2: compact + sort by (score desc, first_g asc), emit top-300 ----
__global__ __launch_bounds__(512) void wbf_sort(const float* __restrict__ recs,
                                                const int* __restrict__ cnts,
                                                float* __restrict__ out) {
    __shared__ u64 s_keys[SORTN];
    const int tid = threadIdx.x;

    int c[NCLS], off[NCLS];
    int n = 0;
    #pragma unroll
    for (int w = 0; w < NCLS; ++w) { c[w] = cnts[w]; off[w] = n; n += c[w]; }

    // compacted key build (class segments are creation-order; key is position-free)
    #pragma unroll
    for (int w = 0; w < NCLS; ++w) {
        const int cw = c[w], ow = off[w];
        for (int j = tid; j < cw; j += 512) {
            const float* r = recs + (size_t)(w * CAP + j) * 8;
            const unsigned sb = __float_as_uint(r[4]);    // score > 0: bits monotone
            const int g = ((const int*)r)[5];
            const int id = w * CAP + j;
            u64 key = ((u64)sb << 32) | ((u64)(unsigned)(0xFFFF - g) << 16) | (u64)id;
            s_keys[ow + j] = ~key;   // ascending sort of ~key == descending of key
        }
    }
    for (int i = n + tid; i < SORTN; i += 512) s_keys[i] = ~0ull;
    __syncthreads();

    // bitonic sort, ascending
    for (int kk = 2; kk <= SORTN; kk <<= 1) {
        for (int jj = kk >> 1; jj > 0; jj >>= 1) {
            for (int i = tid; i < SORTN; i += 512) {
                const int ixj = i ^ jj;
                if (ixj > i) {
                    const u64 a = s_keys[i], b = s_keys[ixj];
                    const bool up = ((i & kk) == 0);
                    if ((a > b) == up) { s_keys[i] = b; s_keys[ixj] = a; }
                }
            }
            __syncthreads();
        }
    }

    // emit top-300
    for (int r = tid; r < POST; r += 512) {
        float* o = out + r * 6;
        if (r < n) {
            const u64 key = ~s_keys[r];
            const int id = (int)(key & 0xFFFFull);
            const float* rec = recs + (size_t)id * 8;
            o[0] = rec[0]; o[1] = rec[1]; o[2] = rec[2]; o[3] = rec[3];
            o[4] = __uint_as_float((unsigned)(key >> 32));
            o[5] = (float)(id >> 9);   // id / CAP == class
        } else {
            o[0] = 0.f; o[1] = 0.f; o[2] = 0.f; o[3] = 0.f; o[4] = 0.f; o[5] = 0.f;
        }
    }
}

extern "C" void kernel_launch(void* const* d_in, const int* in_sizes, int n_in,
                              void* d_out, int out_size, void* d_ws, size_t ws_size,
                              hipStream_t stream) {
    const float* x = (const float*)d_in[0];
    float* out = (float*)d_out;
    int* cnts = (int*)d_ws;                          // 5 ints (always fully written)
    float* recs = (float*)((char*)d_ws + 256);       // 2560 slots x 32 B = 80 KB
    wbf_scan<<<NCLS, 64, 0, stream>>>(x, recs, cnts);
    wbf_sort<<<1, 512, 0, stream>>>(recs, cnts, out);
}

// Round 9
// 395.631 us; speedup vs baseline: 1.2484x; 1.1257x over previous
//
#include <hip/hip_runtime.h>

typedef unsigned long long u64;
typedef unsigned short u16;

#define PRE   2000
#define POST  300
#define NCLS  5
#define CAP   512            // max clusters/dets per class (input has ~400/class)
#define SORTN 2048
#define NTH   320            // 5 waves, one class per wave

// Exact threshold midpoint: fl32(inter/uni) > 0.55f  <=>  inter >= MID*uni (uni>0).
// MID = 0.55f + 2^-25; MID*(24-bit uni) exact in f64 -> bit-exact predicate.
// Validated: absmax == 0.0 in rounds 3-8.
#define MID 0x1.19999A8p-1

// Compile-time unroller: indices are constants at IR-gen, BEFORE SROA runs,
// so all state arrays scalarize into VGPRs (rounds 6-8 spilled because
// #pragma unroll constants arrive only after SROA has already punted).
template <int K> struct IC { static constexpr int v = K; };
template <int N, typename F> __device__ __forceinline__ void unrollN(F&& f) {
    if constexpr (N > 0) { unrollN<N - 1>(f); f(IC<N - 1>{}); }
}

__device__ __forceinline__ float rdlanef(float v, int l) {
    return __int_as_float(__builtin_amdgcn_readlane(__float_as_int(v), l));
}

__global__ __launch_bounds__(NTH, 1) void wbf_fused(const float* __restrict__ x,
                                                    float* __restrict__ out) {
#pragma clang fp contract(off)
    // LDS: 40960 (means, output stage) + 5120 (det lists) + 16384 (keys) + 4 = 62,468 B
    __shared__ float4 s_mean[NCLS * CAP];
    __shared__ u16    s_list[NCLS * CAP];
    __shared__ u64    s_keys[SORTN];      // aliased as class cache in P0/P1
    __shared__ int    s_total;

    const int tid  = threadIdx.x;
    const int w    = tid >> 6;      // class id == wave id
    const int lane = tid & 63;
    const float mycls = (float)w;
    const int base = w * CAP;

    float* s_clsTmp = (float*)s_keys;   // 2000 floats, dead after P1

    // ---- P0: cooperative load of class fields ----
    for (int t = tid; t < PRE; t += NTH) s_clsTmp[t] = x[t * 6 + 5];
    if (tid == 0) s_total = 0;
    __syncthreads();

    // ---- P1: per-wave order-preserving compaction of my class's det indices ----
    int myn = 0;
    for (int t0 = 0; t0 < PRE; t0 += 64) {
        const int t = t0 + lane;
        const bool p = (t < PRE) && (s_clsTmp[t] == mycls);
        const u64 mask = __ballot(p);
        const int pos = myn + __popcll(mask & (((u64)1 << lane) - 1));
        if (p && pos < CAP) s_list[base + pos] = (u16)t;
        myn += __popcll(mask);
    }
    if (myn > CAP) myn = CAP;
    __syncthreads();   // all waves done with s_clsTmp before s_keys reuse

    // ---- P1.5: preload dets (lane-distributed regs) + precompute solo means ----
    // det rank r: lane r&63, reg r>>6.  cluster slot j: lane j&63, reg j>>6.
    float rb0[8], rb1[8], rb2[8], rb3[8], rsc[8];     // det fields
    int   rg[8];                                      // det global index
    float q0[8], q1[8], q2[8], q3[8];                 // solo means (create mean)
    float cm0[8], cm1[8], cm2[8], cm3[8], ca[8];      // cluster means + cached area
    float cs0[8], cs1[8], cs2[8], cs3[8], css[8];     // cluster sums (slot-keyed)
    int   cg[8];                                      // slot meta: cnt<<16 | first_g

    unrollN<8>([&](auto k_) {
        constexpr int K = decltype(k_)::v;
        const int rr = K * 64 + lane;
        rb0[K] = 0.f; rb1[K] = 0.f; rb2[K] = 0.f; rb3[K] = 0.f; rsc[K] = 0.f; rg[K] = 0;
        cm0[K] = 0.f; cm1[K] = 0.f; cm2[K] = 0.f; cm3[K] = 0.f; ca[K] = 0.f;
        cs0[K] = 0.f; cs1[K] = 0.f; cs2[K] = 0.f; cs3[K] = 0.f; css[K] = 0.f; cg[K] = 0;
        if (rr < myn) {
            const int g = s_list[base + rr];
            const float* p = x + g * 6;
            const float2 f01 = *(const float2*)p;
            const float2 f23 = *(const float2*)(p + 2);
            const float2 f45 = *(const float2*)(p + 4);
            rb0[K] = f01.x; rb1[K] = f01.y; rb2[K] = f23.x; rb3[K] = f23.y;
            rsc[K] = f45.x; rg[K] = g;
        }
        // solo mean, exact reference op order: fl(sc*b) then / sc
        const float d = (rr < myn) ? rsc[K] : 1.0f;
        q0[K] = (rsc[K] * rb0[K]) / d; q1[K] = (rsc[K] * rb1[K]) / d;
        q2[K] = (rsc[K] * rb2[K]) / d; q3[K] = (rsc[K] * rb3[K]) / d;
    });

    // ---- P2: per-wave sequential WBF scan — all state in registers ----
    int nc = 0;
    unrollN<8>([&](auto k_) {
        constexpr int K = decltype(k_)::v;
        const int r0 = K * 64;
        if (r0 < myn) {
            const int iend = (myn - r0 < 64) ? (myn - r0) : 64;
            for (int i = 0; i < iend; ++i) {
                // det broadcast via v_readlane (VALU->SGPR, no DS ops)
                const float bx0 = rdlanef(rb0[K], i);
                const float bx1 = rdlanef(rb1[K], i);
                const float bx2 = rdlanef(rb2[K], i);
                const float bx3 = rdlanef(rb3[K], i);
                const float sc  = rdlanef(rsc[K], i);
                const float a1 = (bx2 - bx0) * (bx3 - bx1);
                // create-path values, independent of the scan chain
                const float v0 = rdlanef(q0[K], i), v1 = rdlanef(q1[K], i);
                const float v2 = rdlanef(q2[K], i), v3 = rdlanef(q3[K], i);
                const float va = (v2 - v0) * (v3 - v1);
                const float u0 = sc * bx0, u1 = sc * bx1, u2 = sc * bx2, u3 = sc * bx3;
                const int gmeta = (1 << 16) | __builtin_amdgcn_readlane(rg[K], i);

                // register-resident scan: cluster j = KB*64 + lane
                int foundj = -1;
                unrollN<8>([&](auto kb_) {
                    constexpr int KB = decltype(kb_)::v;
                    if (KB * 64 < nc) {
                        const int j = KB * 64 + lane;
                        const float ltx = fmaxf(bx0, cm0[KB]), lty = fmaxf(bx1, cm1[KB]);
                        const float rbx = fminf(bx2, cm2[KB]), rby = fminf(bx3, cm3[KB]);
                        const float wd = fmaxf(rbx - ltx, 0.f), hg = fmaxf(rby - lty, 0.f);
                        const float inter = wd * hg;
                        const float uni = (a1 + ca[KB]) - inter;
                        const bool pred = (j < nc) && (uni > 0.f) &&
                                          ((double)inter >= MID * (double)uni);
                        const u64 mk = __ballot(pred);
                        if (foundj < 0 && mk) foundj = KB * 64 + (int)__ffsll(mk) - 1;
                    }
                });

                if (foundj < 0) {
                    // CREATE: predicated register writes only, zero chain arithmetic
                    const int ks = nc >> 6, os = nc & 63;
                    unrollN<8>([&](auto s_) {
                        constexpr int KS = decltype(s_)::v;
                        if (ks == KS && lane == os) {
                            cm0[KS] = v0; cm1[KS] = v1; cm2[KS] = v2; cm3[KS] = v3;
                            ca[KS] = va;
                            cs0[KS] = u0; cs1[KS] = u1; cs2[KS] = u2; cs3[KS] = u3;
                            css[KS] = sc; cg[KS] = gmeta;
                        }
                    });
                    nc++;
                } else {
                    // MERGE (rare): fully owner-local update, exact ref op order
                    const int kc = foundj >> 6, oc = foundj & 63;
                    unrollN<8>([&](auto c_) {
                        constexpr int KC = decltype(c_)::v;
                        if (kc == KC && lane == oc) {
                            const float ns0 = cs0[KC] + sc * bx0;
                            const float ns1 = cs1[KC] + sc * bx1;
                            const float ns2 = cs2[KC] + sc * bx2;
                            const float ns3 = cs3[KC] + sc * bx3;
                            const float nss = css[KC] + sc;
                            cs0[KC] = ns0; cs1[KC] = ns1; cs2[KC] = ns2; cs3[KC] = ns3;
                            css[KC] = nss; cg[KC] += 0x10000;
                            const float nm0 = ns0 / nss, nm1 = ns1 / nss;
                            const float nm2 = ns2 / nss, nm3 = ns3 / nss;
                            cm0[KC] = nm0; cm1[KC] = nm1; cm2[KC] = nm2; cm3[KC] = nm3;
                            ca[KC] = (nm2 - nm0) * (nm3 - nm1);
                        }
                    });
                }
            }
        }
    });

    // ---- P2.5: materialize means to LDS for the output gather ----
    unrollN<8>([&](auto kb_) {
        constexpr int KB = decltype(kb_)::v;
        const int j = KB * 64 + lane;
        if (j < nc) s_mean[base + j] = make_float4(cm0[KB], cm1[KB], cm2[KB], cm3[KB]);
    });

    // ---- P3: slot-parallel sort-key build (score desc, first-det-idx asc) ----
    __syncthreads();
    int mybase = 0;
    if (lane == 0 && nc > 0) mybase = atomicAdd(&s_total, nc);
    mybase = __shfl(mybase, 0);
    unrollN<8>([&](auto kb_) {
        constexpr int KB = decltype(kb_)::v;
        const int j = KB * 64 + lane;
        if (j < nc) {
            const int cnt = cg[KB] >> 16;                 // >= 1
            const int g   = cg[KB] & 0xFFFF;              // first det global index
            const float score = css[KB] / (float)cnt;     // exact IEEE div
            const unsigned sb = __float_as_uint(score);   // score > 0: bits monotone
            const int id = base + j;
            u64 key = ((u64)sb << 32) | ((u64)(unsigned)(0xFFFF - g) << 16) | (u64)id;
            s_keys[mybase + j] = ~key;   // ascending sort of ~key == descending of key
        }
    });
    __syncthreads();
    const int n = s_total;
    for (int i = n + tid; i < SORTN; i += NTH) s_keys[i] = ~0ull;
    __syncthreads();

    // ---- P4: bitonic sort, ascending ----
    for (int kk = 2; kk <= SORTN; kk <<= 1) {
        for (int jj = kk >> 1; jj > 0; jj >>= 1) {
            for (int i = tid; i < SORTN; i += NTH) {
                const int ixj = i ^ jj;
                if (ixj > i) {
                    const u64 a = s_keys[i], b = s_keys[ixj];
                    const bool up = ((i & kk) == 0);
                    if ((a > b) == up) { s_keys[i] = b; s_keys[ixj] = a; }
                }
            }
            __syncthreads();
        }
    }

    // ---- P5: emit top-300 ----
    for (int r = tid; r < POST; r += NTH) {
        float* o = out + r * 6;
        if (r < n) {
            const u64 key = ~s_keys[r];
            const int id = (int)(key & 0xFFFFull);
            const float4 mn = s_mean[id];
            o[0] = mn.x; o[1] = mn.y; o[2] = mn.z; o[3] = mn.w;
            o[4] = __uint_as_float((unsigned)(key >> 32));
            o[5] = (float)(id >> 9);   // id / CAP == class
        } else {
            o[0] = 0.f; o[1] = 0.f; o[2] = 0.f; o[3] = 0.f; o[4] = 0.f; o[5] = 0.f;
        }
    }
}

extern "C" void kernel_launch(void* const* d_in, const int* in_sizes, int n_in,
                              void* d_out, int out_size, void* d_ws, size_t ws_size,
                              hipStream_t stream) {
    const float* x = (const float*)d_in[0];
    float* out = (float*)d_out;
    wbf_fused<<<1, NTH, 0, stream>>>(x, out);
}

// Round 10
// 316.789 us; speedup vs baseline: 1.5591x; 1.2489x over previous
//
#include <hip/hip_runtime.h>

typedef unsigned long long u64;
typedef unsigned short u16;

#define PRE   2000
#define POST  300
#define NCLS  5
#define CAP   512            // max dets/clusters per class (input ~400/class)
#define SORTN 2048
#define INF   0x7fffffff

// Exact threshold midpoint: fl32(inter/uni) > 0.55f  <=>  inter >= MID*uni (uni>0).
// MID = 0.55f + 2^-25; MID*(24-bit uni) exact in f64 -> bit-exact predicate.
// Validated: absmax == 0.0 in rounds 3-9.
#define MID 0x1.19999A8p-1

// Compile-time unroller: constant indices at IR-gen (before SROA) so register
// arrays scalarize (validated round 9: killed the scratch spill).
template <int K> struct IC { static constexpr int v = K; };
template <int N, typename F> __device__ __forceinline__ void unrollN(F&& f) {
    if constexpr (N > 0) { unrollN<N - 1>(f); f(IC<N - 1>{}); }
}

__device__ __forceinline__ float rdlanef(float v, int l) {
    return __int_as_float(__builtin_amdgcn_readlane(__float_as_int(v), l));
}

// exact reference IoU>0.55 predicate vs a mean box (a1 = area of det box)
__device__ __forceinline__ bool iou_pred(float bx0, float bx1, float bx2, float bx3,
                                         float a1, float m0, float m1, float m2, float m3,
                                         float a2) {
    const float ltx = fmaxf(bx0, m0), lty = fmaxf(bx1, m1);
    const float rbx = fminf(bx2, m2), rby = fminf(bx3, m3);
    const float wd = fmaxf(rbx - ltx, 0.f), hg = fmaxf(rby - lty, 0.f);
    const float inter = wd * hg;
    const float uni = (a1 + a2) - inter;
    return (uni > 0.f) && ((double)inter >= MID * (double)uni);
}

// ---------- kernel A: candidate matrix M[cls][row rank][8 words of creator-rank bits]
// bit(c) of row r == exact IoU(det r, solo mean of det c) > 0.55, c < r, same class.
// Grid: 5 classes x 32 row-slices of 16 rows. Grid-parallel (also raises clocks).
__global__ __launch_bounds__(64, 1) void wbf_matrix(const float* __restrict__ x,
                                                    u64* __restrict__ M) {
#pragma clang fp contract(off)
    __shared__ u16 s_list[CAP];
    const int lane = threadIdx.x;
    const int cls = blockIdx.x >> 5;
    const int slice = blockIdx.x & 31;
    const float mycls = (float)cls;

    // order-preserving compaction of this class's det indices (single wave)
    int myn = 0;
    for (int t0 = 0; t0 < PRE; t0 += 64) {
        const int t = t0 + lane;
        const bool p = (t < PRE) && (x[t * 6 + 5] == mycls);
        const u64 mask = __ballot(p);
        const int pos = myn + __popcll(mask & (((u64)1 << lane) - 1));
        if (p && pos < CAP) s_list[pos] = (u16)t;
        myn += __popcll(mask);
    }
    if (myn > CAP) myn = CAP;

    // column clusters: lane holds solo mean + area for ranks K*64+lane
    float qc0[8], qc1[8], qc2[8], qc3[8], ac[8];
    unrollN<8>([&](auto k_) {
        constexpr int K = decltype(k_)::v;
        const int c = K * 64 + lane;
        qc0[K] = 0.f; qc1[K] = 0.f; qc2[K] = 0.f; qc3[K] = 0.f; ac[K] = 0.f;
        if (c < myn) {
            const int g = s_list[c];
            const float* p = x + g * 6;
            const float b0 = p[0], b1 = p[1], b2 = p[2], b3 = p[3], sc = p[4];
            // solo mean, exact reference op order: fl(sc*b) then / sc
            qc0[K] = (sc * b0) / sc; qc1[K] = (sc * b1) / sc;
            qc2[K] = (sc * b2) / sc; qc3[K] = (sc * b3) / sc;
            ac[K] = (qc2[K] - qc0[K]) * (qc3[K] - qc1[K]);
        }
    });

    const int rlo = slice * 16;
    const int rhi = (rlo + 16 < myn) ? rlo + 16 : myn;
    for (int r = rlo; r < rhi; ++r) {
        const int g = s_list[r];
        const float* p = x + g * 6;
        const float bx0 = p[0], bx1 = p[1], bx2 = p[2], bx3 = p[3];
        const float a1 = (bx2 - bx0) * (bx3 - bx1);
        unrollN<8>([&](auto w_) {
            constexpr int W = decltype(w_)::v;
            const int c = W * 64 + lane;
            const bool pred = (c < r) &&
                iou_pred(bx0, bx1, bx2, bx3, a1, qc0[W], qc1[W], qc2[W], qc3[W], ac[W]);
            const u64 bits = __ballot(pred);
            if (lane == 0) M[((size_t)(cls * CAP + r)) * 8 + W] = bits;
        });
    }
}

// ---------- kernel B: per-class serial scan. clean clusters = alive-bit + matrix row;
// dirty clusters (merged at least once) tracked in lane registers (+ small LDS overflow).
__global__ __launch_bounds__(64, 1) void wbf_scan(const float* __restrict__ x,
                                                  const u64* __restrict__ M,
                                                  float* __restrict__ recs,
                                                  int* __restrict__ cnts) {
#pragma clang fp contract(off)
    __shared__ u64   s_mtx[CAP * 8];     // 32 KB: this class's matrix rows
    __shared__ u16   s_list[CAP];
    __shared__ float s_dov[16][12];      // dirty overflow: m0..3, s0..3, ss, rank, g, cnt

    const int lane = threadIdx.x;
    const int w = blockIdx.x;
    const float mycls = (float)w;

    // ---- compaction (deterministic, identical to kernel A) ----
    int myn = 0;
    for (int t0 = 0; t0 < PRE; t0 += 64) {
        const int t = t0 + lane;
        const bool p = (t < PRE) && (x[t * 6 + 5] == mycls);
        const u64 mask = __ballot(p);
        const int pos = myn + __popcll(mask & (((u64)1 << lane) - 1));
        if (p && pos < CAP) s_list[pos] = (u16)t;
        myn += __popcll(mask);
    }
    if (myn > CAP) myn = CAP;

    // ---- stage matrix rows to LDS (single wave, in-order DS) ----
    {
        const ulonglong2* Mg = (const ulonglong2*)(M + (size_t)w * CAP * 8);
        ulonglong2* Ml = (ulonglong2*)s_mtx;
        for (int it = lane; it < CAP * 4; it += 64) Ml[it] = Mg[it];
    }

    // ---- preload det fields, rank-indexed lane-distributed ----
    float rb0[8], rb1[8], rb2[8], rb3[8], rsc[8];
    int   rg[8];
    unrollN<8>([&](auto k_) {
        constexpr int K = decltype(k_)::v;
        const int rr = K * 64 + lane;
        rb0[K] = 0.f; rb1[K] = 0.f; rb2[K] = 0.f; rb3[K] = 0.f; rsc[K] = 1.f; rg[K] = 0;
        if (rr < myn) {
            const int g = s_list[rr];
            const float* p = x + g * 6;
            const float2 f01 = *(const float2*)p;
            const float2 f23 = *(const float2*)(p + 2);
            rb0[K] = f01.x; rb1[K] = f01.y; rb2[K] = f23.x; rb3[K] = f23.y;
            rsc[K] = p[4]; rg[K] = g;
        }
    });

    // ---- serial scan state ----
    u64 alive[8];
    unrollN<8>([&](auto k_) { alive[decltype(k_)::v] = 0ull; });
    // dirty entry per lane: mean, area, sums, ss, creator rank, g, cnt
    float dm0 = 0.f, dm1 = 0.f, dm2 = 0.f, dm3 = 0.f, da = 0.f;
    float e0 = 0.f, e1 = 0.f, e2 = 0.f, e3 = 0.f, ess = 0.f;
    int   drk = INF, dgi = 0, dct = 0;
    int dirtyCnt = 0;

    // row prefetch (1 ahead; LDS latency ~120cyc ~ one det of work)
    ulonglong2 pfa, pfb, pfc, pfd;
    {
        const ulonglong2* rp = (const ulonglong2*)&s_mtx[0];
        pfa = rp[0]; pfb = rp[1]; pfc = rp[2]; pfd = rp[3];
    }

    unrollN<8>([&](auto k_) {
        constexpr int K = decltype(k_)::v;
        if (K * 64 < myn) {
            const int iend = (myn - K * 64 < 64) ? (myn - K * 64) : 64;
            for (int i = 0; i < iend; ++i) {
                const int r = K * 64 + i;
                // consume prefetched row; issue next
                u64 row[8];
                row[0] = pfa.x; row[1] = pfa.y; row[2] = pfb.x; row[3] = pfb.y;
                row[4] = pfc.x; row[5] = pfc.y; row[6] = pfd.x; row[7] = pfd.y;
                {
                    const int rn = (r + 1 < myn) ? r + 1 : r;
                    const ulonglong2* rp = (const ulonglong2*)&s_mtx[(size_t)rn * 8];
                    pfa = rp[0]; pfb = rp[1]; pfc = rp[2]; pfd = rp[3];
                }
                // det broadcast (compile-time K, uniform i)
                const float bx0 = rdlanef(rb0[K], i);
                const float bx1 = rdlanef(rb1[K], i);
                const float bx2 = rdlanef(rb2[K], i);
                const float bx3 = rdlanef(rb3[K], i);
                const float sc  = rdlanef(rsc[K], i);
                const float a1 = (bx2 - bx0) * (bx3 - bx1);

                // clean first-match: masked row, first set bit == min creator rank
                int rank_c = INF;
                unrollN<8>([&](auto w_) {
                    constexpr int W = decltype(w_)::v;
                    const u64 m = row[W] & alive[W];
                    if (rank_c == INF && m) rank_c = W * 64 + (int)__builtin_ctzll(m);
                });

                // dirty matches (means evolve -> evaluate live)
                int rank_d = INF, wl = -1;
                if (dirtyCnt > 0) {
                    const bool v = lane < dirtyCnt;
                    const bool p = v && iou_pred(bx0, bx1, bx2, bx3, a1,
                                                 dm0, dm1, dm2, dm3, da);
                    u64 mk = __ballot(p);
                    while (mk) {
                        const int l = (int)__builtin_ctzll(mk);
                        mk &= mk - 1;
                        const int rk = __builtin_amdgcn_readlane(drk, l);
                        if (rk < rank_d) { rank_d = rk; wl = l; }
                    }
                    if (dirtyCnt > 64) {
                        const int no = (dirtyCnt - 64 < 16) ? dirtyCnt - 64 : 16;
                        for (int o = 0; o < no; ++o) {
                            const float m0 = s_dov[o][0], m1 = s_dov[o][1];
                            const float m2 = s_dov[o][2], m3 = s_dov[o][3];
                            const float ar = (m2 - m0) * (m3 - m1);
                            if (iou_pred(bx0, bx1, bx2, bx3, a1, m0, m1, m2, m3, ar)) {
                                const int rk = ((const int*)s_dov[o])[9];
                                if (rk < rank_d) { rank_d = rk; wl = 64 + o; }
                            }
                        }
                    }
                }

                if (rank_c == INF && rank_d == INF) {
                    // CREATE: one bit — the cluster's data is this det's registers
                    alive[K] |= 1ull << i;
                } else if (rank_c < rank_d) {
                    // MERGE into clean cluster rc: goes dirty
                    const int rc = rank_c;
                    unrollN<8>([&](auto w_) {
                        constexpr int W = decltype(w_)::v;
                        if ((rc >> 6) == W) alive[W] &= ~(1ull << (rc & 63));
                    });
                    float cb0 = 0.f, cb1 = 0.f, cb2 = 0.f, cb3 = 0.f, csc = 1.f;
                    int cgi = 0;
                    unrollN<8>([&](auto w_) {
                        constexpr int W = decltype(w_)::v;
                        if ((rc >> 6) == W) {
                            const int l = rc & 63;
                            cb0 = rdlanef(rb0[W], l); cb1 = rdlanef(rb1[W], l);
                            cb2 = rdlanef(rb2[W], l); cb3 = rdlanef(rb3[W], l);
                            csc = rdlanef(rsc[W], l);
                            cgi = __builtin_amdgcn_readlane(rg[W], l);
                        }
                    });
                    // exact ref op order: solo sums fl(csc*cb), += fl(sc*bx), div
                    const float ns0 = (csc * cb0) + sc * bx0;
                    const float ns1 = (csc * cb1) + sc * bx1;
                    const float ns2 = (csc * cb2) + sc * bx2;
                    const float ns3 = (csc * cb3) + sc * bx3;
                    const float nss = csc + sc;
                    const float nm0 = ns0 / nss, nm1 = ns1 / nss;
                    const float nm2 = ns2 / nss, nm3 = ns3 / nss;
                    if (dirtyCnt < 64) {
                        if (lane == dirtyCnt) {
                            dm0 = nm0; dm1 = nm1; dm2 = nm2; dm3 = nm3;
                            da = (nm2 - nm0) * (nm3 - nm1);
                            e0 = ns0; e1 = ns1; e2 = ns2; e3 = ns3; ess = nss;
                            drk = rc; dgi = cgi; dct = 2;
                        }
                    } else if (dirtyCnt - 64 < 16) {
                        const int o = dirtyCnt - 64;
                        if (lane == 0) {
                            s_dov[o][0] = nm0; s_dov[o][1] = nm1;
                            s_dov[o][2] = nm2; s_dov[o][3] = nm3;
                            s_dov[o][4] = ns0; s_dov[o][5] = ns1;
                            s_dov[o][6] = ns2; s_dov[o][7] = ns3;
                            s_dov[o][8] = nss;
                            ((int*)s_dov[o])[9] = rc; ((int*)s_dov[o])[10] = cgi;
                            ((int*)s_dov[o])[11] = 2;
                        }
                    }
                    dirtyCnt++;
                } else {
                    // MERGE into existing dirty cluster
                    if (wl < 64) {
                        if (lane == wl) {
                            e0 = e0 + sc * bx0; e1 = e1 + sc * bx1;
                            e2 = e2 + sc * bx2; e3 = e3 + sc * bx3;
                            ess = ess + sc; dct++;
                            dm0 = e0 / ess; dm1 = e1 / ess;
                            dm2 = e2 / ess; dm3 = e3 / ess;
                            da = (dm2 - dm0) * (dm3 - dm1);
                        }
                    } else {
                        const int o = wl - 64;
                        const float f0 = s_dov[o][4] + sc * bx0;
                        const float f1 = s_dov[o][5] + sc * bx1;
                        const float f2 = s_dov[o][6] + sc * bx2;
                        const float f3 = s_dov[o][7] + sc * bx3;
                        const float fs = s_dov[o][8] + sc;
                        if (lane == 0) {
                            s_dov[o][0] = f0 / fs; s_dov[o][1] = f1 / fs;
                            s_dov[o][2] = f2 / fs; s_dov[o][3] = f3 / fs;
                            s_dov[o][4] = f0; s_dov[o][5] = f1;
                            s_dov[o][6] = f2; s_dov[o][7] = f3;
                            s_dov[o][8] = fs;
                            ((int*)s_dov[o])[11] += 1;
                        }
                    }
                }
            }
        }
    });

    // ---- emit compacted records: clean (solo mean, score=sc) then dirty ----
    int wo = 0;
    unrollN<8>([&](auto k_) {
        constexpr int K = decltype(k_)::v;
        const u64 am = alive[K];
        const bool pred = (am >> lane) & 1;
        if (pred) {
            const int pos = wo + (int)__popcll(am & (((u64)1 << lane) - 1));
            // solo mean, exact: fl(sc*b)/sc (score = ss/1.0 = sc exactly)
            const float sc = rsc[K];
            float* rec = recs + (size_t)(w * CAP + pos) * 8;
            rec[0] = (sc * rb0[K]) / sc; rec[1] = (sc * rb1[K]) / sc;
            rec[2] = (sc * rb2[K]) / sc; rec[3] = (sc * rb3[K]) / sc;
            rec[4] = sc;
            ((int*)rec)[5] = rg[K];
        }
        wo += (int)__popcll(am);
    });
    const int nreg = (dirtyCnt < 64) ? dirtyCnt : 64;
    if (lane < nreg) {
        float* rec = recs + (size_t)(w * CAP + wo + lane) * 8;
        rec[0] = dm0; rec[1] = dm1; rec[2] = dm2; rec[3] = dm3;
        rec[4] = ess / (float)dct;          // exact IEEE div
        ((int*)rec)[5] = dgi;
    }
    const int nov = (dirtyCnt > 64) ? ((dirtyCnt - 64 < 16) ? dirtyCnt - 64 : 16) : 0;
    for (int o = 0; o < nov; ++o) {
        if (lane == 0) {
            float* rec = recs + (size_t)(w * CAP + wo + nreg + o) * 8;
            rec[0] = s_dov[o][0]; rec[1] = s_dov[o][1];
            rec[2] = s_dov[o][2]; rec[3] = s_dov[o][3];
            rec[4] = s_dov[o][8] / (float)(((const int*)s_dov[o])[11]);
            ((int*)rec)[5] = ((const int*)s_dov[o])[10];
        }
    }
    if (lane == 0) cnts[w] = wo + nreg + nov;
}

// ---------- kernel C: compact + sort by (score desc, first_g asc), emit top-300 ----
__global__ __launch_bounds__(512) void wbf_sort(const float* __restrict__ recs,
                                                const int* __restrict__ cnts,
                                                float* __restrict__ out) {
    __shared__ u64 s_keys[SORTN];
    const int tid = threadIdx.x;

    int c[NCLS], off[NCLS];
    int n = 0;
    #pragma unroll
    for (int w = 0; w < NCLS; ++w) { c[w] = cnts[w]; off[w] = n; n += c[w]; }
    if (n > PRE) n = PRE;

    #pragma unroll
    for (int w = 0; w < NCLS; ++w) {
        const int cw = c[w], ow = off[w];
        for (int j = tid; j < cw; j += 512) {
            const float* r = recs + (size_t)(w * CAP + j) * 8;
            const unsigned sb = __float_as_uint(r[4]);    // score > 0: bits monotone
            const int g = ((const int*)r)[5];
            const int id = w * CAP + j;
            u64 key = ((u64)sb << 32) | ((u64)(unsigned)(0xFFFF - g) << 16) | (u64)id;
            s_keys[ow + j] = ~key;   // ascending sort of ~key == descending of key
        }
    }
    for (int i = n + tid; i < SORTN; i += 512) s_keys[i] = ~0ull;
    __syncthreads();

    for (int kk = 2; kk <= SORTN; kk <<= 1) {
        for (int jj = kk >> 1; jj > 0; jj >>= 1) {
            for (int i = tid; i < SORTN; i += 512) {
                const int ixj = i ^ jj;
                if (ixj > i) {
                    const u64 a = s_keys[i], b = s_keys[ixj];
                    const bool up = ((i & kk) == 0);
                    if ((a > b) == up) { s_keys[i] = b; s_keys[ixj] = a; }
                }
            }
            __syncthreads();
        }
    }

    for (int r = tid; r < POST; r += 512) {
        float* o = out + r * 6;
        if (r < n) {
            const u64 key = ~s_keys[r];
            const int id = (int)(key & 0xFFFFull);
            const float* rec = recs + (size_t)id * 8;
            o[0] = rec[0]; o[1] = rec[1]; o[2] = rec[2]; o[3] = rec[3];
            o[4] = __uint_as_float((unsigned)(key >> 32));
            o[5] = (float)(id >> 9);   // id / CAP == class
        } else {
            o[0] = 0.f; o[1] = 0.f; o[2] = 0.f; o[3] = 0.f; o[4] = 0.f; o[5] = 0.f;
        }
    }
}

extern "C" void kernel_launch(void* const* d_in, const int* in_sizes, int n_in,
                              void* d_out, int out_size, void* d_ws, size_t ws_size,
                              hipStream_t stream) {
    const float* x = (const float*)d_in[0];
    float* out = (float*)d_out;
    // ws layout (requires ~246 KB): matrix 160 KB | cnts | recs 80 KB
    u64* M      = (u64*)d_ws;
    int* cnts   = (int*)((char*)d_ws + NCLS * CAP * 8 * sizeof(u64));
    float* recs = (float*)((char*)d_ws + NCLS * CAP * 8 * sizeof(u64) + 256);
    wbf_matrix<<<NCLS * 32, 64, 0, stream>>>(x, M);
    wbf_scan<<<NCLS, 64, 0, stream>>>(x, M, recs, cnts);
    wbf_sort<<<1, 512, 0, stream>>>(recs, cnts, out);
}